// Round 4
// baseline (240.652 us; speedup 1.0000x reference)
//
#include <hip/hip_runtime.h>
#include <math.h>

#define Bb 16
#define Nn 2048
#define Ff 2048
#define Ee 128
#define Kk 10
#define S2FC 8              // fact chunks in k_s2t
#define S2F (Ff / S2FC)     // 256 facts per block
#define FS 2                // fact-split factor in k_spmax (interleaved chunks)

typedef __attribute__((ext_vector_type(8))) short short8;
typedef __attribute__((ext_vector_type(4))) float f32x4;

// ---------------- helpers ----------------
__device__ inline float wave_sum(float x) {
    for (int o = 32; o; o >>= 1) x += __shfl_down(x, o);
    return x;  // valid in lane 0
}

// split fp32 -> bf16 hi (truncate) + bf16 lo (truncate of exact remainder)
__device__ inline void bsplit(float x, unsigned short& h, unsigned short& l) {
    unsigned int u = __float_as_uint(x);
    h = (unsigned short)(u >> 16);
    float hf = __uint_as_float(u & 0xFFFF0000u);
    l = (unsigned short)(__float_as_uint(x - hf) >> 16);
}

__device__ inline void atomic_fmax_pos(float* addr, float v) {
    // valid for non-negative floats: bit pattern order == float order
    atomicMax((unsigned int*)addr, __float_as_uint(v));
}

// ---------------- K1: pfe = facts(+inline hops) [0..127] + fact pre-split [128..4223]
//                       + entity norms / sp zero-init [4224..12415] ----------------
__global__ __launch_bounds__(256) void k_pfe(
    const float* __restrict__ rel, const float* __restrict__ arg1,
    const float* __restrict__ arg2, const float* __restrict__ frel,
    const float* __restrict__ fa1, const float* __restrict__ fa2,
    const float* __restrict__ ent, const float* __restrict__ hop_W,
    const float* __restrict__ hop_b, const int* __restrict__ nb_facts,
    unsigned short* __restrict__ B0, unsigned short* __restrict__ B1,
    float* __restrict__ ent_norm, float* __restrict__ c0, float* __restrict__ c1,
    float* __restrict__ s2b0, float* __restrict__ s2b1,
    float* __restrict__ sp0, float* __restrict__ sp1, float* __restrict__ out) {
    int bx = blockIdx.x;
    int tid = threadIdx.x;
    if (bx < 128) {
        // ---- facts: 256 facts/block, hops recomputed per block (identical fp order) ----
        int fcb = bx & 7, b = bx >> 3;
        int nbf = nb_facts[b];
        if (fcb * 256 >= nbf) {
            // whole block past valid facts: outputs are exactly -INF, skip all compute
            int f = fcb * 256 + tid;
            size_t o = (size_t)b * Ff + f;
            const float NI = -INFINITY;
            c0[o] = NI; c1[o] = NI; s2b0[o] = NI; s2b1[o] = NI;
            return;
        }
        __shared__ float q[7][Ee];     // rel, arg1, arg2, h10(rj0), h11(rj2), h20(rj1), h21(rj3)
        __shared__ float bred[4];
        if (tid < 128) {
            q[0][tid] = rel[b * Ee + tid];
            q[1][tid] = arg1[b * Ee + tid];
            q[2][tid] = arg2[b * Ee + tid];
        }
        __syncthreads();
        {   // hop projections: threads 0-127 do rj0,rj1; threads 128-255 do rj2,rj3
            int e = tid & 127, hf = tid >> 7;
            const float* W0 = hop_W + (size_t)(hf * 2) * Ee * Ee;
            const float* W1 = W0 + (size_t)Ee * Ee;
            float a0 = hop_b[(hf * 2) * Ee + e];
            float a1 = hop_b[(hf * 2 + 1) * Ee + e];
            for (int qq = 0; qq < Ee; ++qq) {
                float rq = q[0][qq];
                a0 += rq * W0[qq * Ee + e];
                a1 += rq * W1[qq * Ee + e];
            }
            q[3 + hf][e] = a0;   // hf0 -> q3 (h1 r0), hf1 -> q4 (h1 r1)
            q[5 + hf][e] = a1;   // hf0 -> q5 (h2 r0), hf1 -> q6 (h2 r1)
        }
        __syncthreads();

        int f = fcb * 256 + tid;
        const float* pr = frel + ((size_t)b * Ff + f) * Ee;
        const float* p1 = fa1 + ((size_t)b * Ff + f) * Ee;
        const float* p2 = fa2 + ((size_t)b * Ff + f) * Ee;
        float d_rr = 0, d_a11 = 0, d_a22 = 0, d_h10 = 0, d_h11 = 0, d_h20 = 0, d_h21 = 0;
        float d_a12 = 0, d_a21 = 0, n1 = 0, n2 = 0;
#pragma unroll 8
        for (int e0 = 0; e0 < Ee; e0 += 4) {
            float4 vr4 = *(const float4*)(pr + e0);
            float4 v14 = *(const float4*)(p1 + e0);
            float4 v24 = *(const float4*)(p2 + e0);
            const float* vrp = (const float*)&vr4;
            const float* v1p = (const float*)&v14;
            const float* v2p = (const float*)&v24;
#pragma unroll
            for (int j = 0; j < 4; ++j) {
                int e = e0 + j;
                float fr = vrp[j], f1 = v1p[j], f2 = v2p[j];
                float t;
                t = q[0][e] - fr; d_rr  += t * t;
                t = q[1][e] - f1; d_a11 += t * t;
                t = q[2][e] - f2; d_a22 += t * t;
                t = q[3][e] - fr; d_h10 += t * t;
                t = q[4][e] - fr; d_h11 += t * t;
                t = q[5][e] - fr; d_h20 += t * t;
                t = q[6][e] - fr; d_h21 += t * t;
                t = q[1][e] - f2; d_a12 += t * t;
                t = q[2][e] - f1; d_a21 += t * t;
                n1 += f1 * f1; n2 += f2 * f2;
            }
        }
        bool valid = f < nbf;
        const float NI = -INFINITY;
        size_t o = (size_t)b * Ff + f;
        c0[o]   = valid ? (-0.5f * (d_h10 + d_a11 + n2)) : NI;
        c1[o]   = valid ? (-0.5f * (d_h11 + d_a12 + n1)) : NI;
        s2b0[o] = valid ? (-0.5f * (d_h20 + d_a22)) : NI;
        s2b1[o] = valid ? (-0.5f * (d_h21 + d_a21)) : NI;
        // scores_0: block-level max of lsc, ONE atomic per block
        float lsc = valid ? (-0.5f * (d_rr + d_a11 + d_a22)) : NI;
        for (int m = 32; m; m >>= 1) lsc = fmaxf(lsc, __shfl_down(lsc, m));
        if ((tid & 63) == 0) bred[tid >> 6] = lsc;
        __syncthreads();
        if (tid == 0) {
            float m = fmaxf(fmaxf(bred[0], bred[1]), fmaxf(bred[2], bred[3]));
            atomic_fmax_pos(out + b, expf(m));
        }
    } else if (bx < 128 + 4096) {
        // ---- fact pre-split into MFMA-fragment order (LDS transpose -> coalesced stores) ----
        __shared__ uint4 tlds[16 * 33];   // [f(16)][stride 33: oct(16)*2 + pad]
        int bxx = bx - 128;
        int y = bxx >> 11, bxi = bxx & 2047;
        int oct = tid & 15, fl = tid >> 4;
        int b = bxi >> 7, fbase = (bxi & 127) * 16;
        const float* src = (y == 0) ? fa2 : fa1;    // r=0 scans fa2, r=1 scans fa1
        const float* s = src + ((size_t)b * Ff + fbase + fl) * Ee + oct * 8;
        float4 v0 = *(const float4*)s;
        float4 v1 = *(const float4*)(s + 4);
        float xs[8] = {v0.x, v0.y, v0.z, v0.w, v1.x, v1.y, v1.z, v1.w};
        unsigned short hi[8], lo[8];
#pragma unroll
        for (int j = 0; j < 8; ++j) bsplit(xs[j], hi[j], lo[j]);
        uint4 ph, pl;
        ph.x = (unsigned)hi[0] | ((unsigned)hi[1] << 16);
        ph.y = (unsigned)hi[2] | ((unsigned)hi[3] << 16);
        ph.z = (unsigned)hi[4] | ((unsigned)hi[5] << 16);
        ph.w = (unsigned)hi[6] | ((unsigned)hi[7] << 16);
        pl.x = (unsigned)lo[0] | ((unsigned)lo[1] << 16);
        pl.y = (unsigned)lo[2] | ((unsigned)lo[3] << 16);
        pl.z = (unsigned)lo[4] | ((unsigned)lo[5] << 16);
        pl.w = (unsigned)lo[6] | ((unsigned)lo[7] << 16);
        tlds[fl * 33 + oct * 2]     = ph;
        tlds[fl * 33 + oct * 2 + 1] = pl;
        __syncthreads();
        // write phase: dense 16B/lane, 256B contiguous per 16-lane group
        int octw = tid >> 4, u0 = tid & 15;       // u = uint4 index within this oct's 512B run
        unsigned short* obase = ((y == 0) ? B0 : B1) +
                                (((size_t)b * 16 + octw) * Ff + fbase) * 16;
        int f0 = u0 >> 1, p0 = u0 & 1;
        int f1 = f0 + 8;
        *(uint4*)(obase + (size_t)u0 * 8)        = tlds[f0 * 33 + octw * 2 + p0];
        *(uint4*)(obase + (size_t)(u0 + 16) * 8) = tlds[f1 * 33 + octw * 2 + p0];
    } else {
        // ---- entity self-norms + sp zero-init: 8192 blocks, 4 rows each ----
        int row  = (bx - (128 + 4096)) * 4 + (tid >> 6);
        int lane = tid & 63;
        const float* p = ent + (size_t)row * Ee;
        float a = p[lane], c = p[lane + 64];
        float s = wave_sum(a * a + c * c);
        if (lane == 0) {
            ent_norm[row] = s;
            sp0[row] = 0.0f;   // identity for atomic fmax of positive exp()
            sp1[row] = 0.0f;
        }
    }
}

// ---------------- K2: fused bias+max GEMM, BM=256 (8 waves) to halve B L2-traffic ----
#define BMs 256

__global__ __launch_bounds__(512, 2) void k_spmax_mfma(
    const float* __restrict__ ent, const unsigned short* __restrict__ B0,
    const unsigned short* __restrict__ B1, const float* __restrict__ c0,
    const float* __restrict__ c1, const float* __restrict__ ent_norm,
    const int* __restrict__ nb_facts, const int* __restrict__ nb_entities,
    float* __restrict__ sp0, float* __restrict__ sp1) {
    // same-slice blocks are 32 apart in bid -> same XCD (mod 8)
    int bid = blockIdx.x;
    int br = bid & 31, nblk = (bid >> 5) & 7, h = bid >> 8;   // h = fact-half
    int b = br >> 1, r = br & 1;
    const unsigned short* Bt = (r == 0) ? B0 : B1;
    const float* cb = ((r == 0) ? c0 : c1) + (size_t)b * Ff;
    float* sp = ((r == 0) ? sp0 : sp1) + (size_t)b * Nn;

    int tid = threadIdx.x;
    int ne = nb_entities[b];
    if (nblk * BMs >= ne) return;            // sp pre-zeroed; nothing to do
    int nch = (nb_facts[b] + 63) >> 6;       // live fact chunks
    if (h >= nch) return;                    // defensive

    __shared__ unsigned short alds[4 * 4 * 4 * 64 * 8];   // 64KB A-lo fragments (wm,i,ks,lane)

    int wave = tid >> 6, lane = tid & 63;
    int wm = wave >> 1, wn = wave & 1;       // wm 0..3, wn 0..1
    int lane15 = lane & 15, quad = lane >> 4;

    // ---- A-hi fragments in registers; A-lo staged once to LDS ----
    short8 ah[4][4];
    {
        const float* abase = ent + ((size_t)b * Nn + (size_t)nblk * BMs + wm * 64) * Ee;
#pragma unroll
        for (int i = 0; i < 4; ++i)
#pragma unroll
            for (int ks = 0; ks < 4; ++ks) {
                const float* p = abase + (size_t)(i * 16 + lane15) * Ee + ks * 32 + quad * 8;
                float4 v0 = *(const float4*)p;
                float4 v1 = *(const float4*)(p + 4);
                float xs[8] = {v0.x, v0.y, v0.z, v0.w, v1.x, v1.y, v1.z, v1.w};
                short8 hi8, lo8;
#pragma unroll
                for (int j = 0; j < 8; ++j) {
                    unsigned short hh, ll;
                    bsplit(xs[j], hh, ll);
                    hi8[j] = (short)hh;
                    lo8[j] = (short)ll;
                }
                ah[i][ks] = hi8;
                if (wn == 0)
                    *(short8*)&alds[(((wm * 4 + i) * 4 + ks) * 64 + lane) * 8] = lo8;
            }
    }
    __syncthreads();

    // wave-invariant B base: unit (b, oct=ks*4+quad, row=wn*32+lane15)
    const unsigned short* bbase =
        Bt + ((((size_t)b * 16 + quad) * Ff) + wn * 32 + lane15) * 16;

    // prefetch first chunk's B fragments (chunk h)
    short8 pbh0[4], pbl0[4], pbh1[4], pbl1[4];
#pragma unroll
    for (int ks = 0; ks < 4; ++ks) {
        const unsigned short* p0 = bbase + ((size_t)ks * 4 * Ff + h * 64) * 16;
        pbh0[ks] = *(const short8*)p0;
        pbl0[ks] = *(const short8*)(p0 + 8);
        pbh1[ks] = *(const short8*)(p0 + 256);
        pbl1[ks] = *(const short8*)(p0 + 264);
    }
    // A-lo double buffer: even ks -> bufA, odd ks -> bufB
    short8 bufA[4], bufB[4];
#pragma unroll
    for (int i = 0; i < 4; ++i)
        bufA[i] = *(short8*)&alds[(((wm * 4 + i) * 4 + 0) * 64 + lane) * 8];

    float mmax[4][4];
#pragma unroll
    for (int i = 0; i < 4; ++i)
#pragma unroll
        for (int rr = 0; rr < 4; ++rr) mmax[i][rr] = -INFINITY;

    for (int c = h; c < nch; c += FS) {
        int f0 = c * 64;
        float cj0 = cb[f0 + wn * 32 + lane15];
        float cj1 = cb[f0 + wn * 32 + 16 + lane15];
        f32x4 acc[4][2];
#pragma unroll
        for (int i = 0; i < 4; ++i) {
            acc[i][0] = (f32x4){cj0, cj0, cj0, cj0};   // bias pre-loaded into accumulator
            acc[i][1] = (f32x4){cj1, cj1, cj1, cj1};
        }
        int fn = ((c + FS < nch) ? (c + FS) : h) * 64;   // wraps (harmless redundant load)

#pragma unroll
        for (int ks = 0; ks < 4; ++ks) {
            short8 bh0 = pbh0[ks], bl0 = pbl0[ks], bh1 = pbh1[ks], bl1 = pbl1[ks];
            // prefetch next chunk, same ks (stays in flight across this ks's MFMAs)
            const unsigned short* p0 = bbase + ((size_t)ks * 4 * Ff + fn) * 16;
            pbh0[ks] = *(const short8*)p0;
            pbl0[ks] = *(const short8*)(p0 + 8);
            pbh1[ks] = *(const short8*)(p0 + 256);
            pbl1[ks] = *(const short8*)(p0 + 264);
            // A-lo: use cur buffer, prefetch next ks into other buffer
            short8* cur = (ks & 1) ? bufB : bufA;
            short8* nxt = (ks & 1) ? bufA : bufB;
            int nks = (ks + 1) & 3;
#pragma unroll
            for (int i = 0; i < 4; ++i)
                nxt[i] = *(short8*)&alds[(((wm * 4 + i) * 4 + nks) * 64 + lane) * 8];
#pragma unroll
            for (int i = 0; i < 4; ++i) {
                acc[i][0] = __builtin_amdgcn_mfma_f32_16x16x32_bf16(ah[i][ks], bh0, acc[i][0], 0, 0, 0);
                acc[i][0] = __builtin_amdgcn_mfma_f32_16x16x32_bf16(cur[i],    bh0, acc[i][0], 0, 0, 0);
                acc[i][0] = __builtin_amdgcn_mfma_f32_16x16x32_bf16(ah[i][ks], bl0, acc[i][0], 0, 0, 0);
                acc[i][1] = __builtin_amdgcn_mfma_f32_16x16x32_bf16(ah[i][ks], bh1, acc[i][1], 0, 0, 0);
                acc[i][1] = __builtin_amdgcn_mfma_f32_16x16x32_bf16(cur[i],    bh1, acc[i][1], 0, 0, 0);
                acc[i][1] = __builtin_amdgcn_mfma_f32_16x16x32_bf16(ah[i][ks], bl1, acc[i][1], 0, 0, 0);
            }
        }

#pragma unroll
        for (int j = 0; j < 2; ++j)
#pragma unroll
            for (int i = 0; i < 4; ++i)
#pragma unroll
                for (int rr = 0; rr < 4; ++rr)
                    mmax[i][rr] = fmaxf(mmax[i][rr], acc[i][j][rr]);
    }

    // ---- reduce across 16 lane15 columns in-wave, then across wn via LDS (reuse alds) ----
    __syncthreads();
    float* red = (float*)alds;   // [256][2]
#pragma unroll
    for (int i = 0; i < 4; ++i)
#pragma unroll
        for (int rr = 0; rr < 4; ++rr) {
            float v = mmax[i][rr];
#pragma unroll
            for (int m = 1; m < 16; m <<= 1) v = fmaxf(v, __shfl_xor(v, m));
            if (lane15 == 0) red[(wm * 64 + i * 16 + quad * 4 + rr) * 2 + wn] = v;
        }
    __syncthreads();
    if (tid < BMs) {
        float m = fmaxf(red[tid * 2], red[tid * 2 + 1]);
        int n = nblk * BMs + tid;
        if (n < ne)
            atomic_fmax_pos(&sp[n], expf(m - 0.5f * ent_norm[(size_t)b * Nn + n]));
    }
}

// ---------------- K3: tail = in-block topk (wave 0) + second-hop rescore + ONE atomic/block ----
__global__ __launch_bounds__(256) void k_s2t(
    const float* __restrict__ ent, const float* __restrict__ fa1,
    const float* __restrict__ fa2, const float* __restrict__ s2b0,
    const float* __restrict__ s2b1, const float* __restrict__ sp0,
    const float* __restrict__ sp1, const int* __restrict__ nb_facts,
    float* __restrict__ out) {
    int fc = blockIdx.x, b = blockIdx.y, r = blockIdx.z;
    if (fc * S2F >= nb_facts[b]) return;   // all facts -INF: atomic would be max(out, 0) = no-op
    const float* factX = (r == 0) ? fa1 : fa2;   // z compares vs fa1 (r=0) / fa2 (r=1)
    const float* s2b   = ((r == 0) ? s2b0 : s2b1) + (size_t)b * Ff;
    const float* sp    = ((r == 0) ? sp0 : sp1) + (size_t)b * Nn;

    __shared__ float zsc[Kk];
    __shared__ int   zidx[Kk];
    __shared__ float zsh[Kk][Ee];
    __shared__ float znorm[Kk];
    __shared__ float red[4][Kk];
    __shared__ float rules[Kk];

    int tid = threadIdx.x;
    int wv = tid >> 6, lane = tid & 63;

    if (wv == 0) {   // single-wave top-K, jax-stable ties (lowest index wins)
        float v[Nn / 64];
#pragma unroll
        for (int i = 0; i < Nn / 64; ++i) v[i] = sp[i * 64 + lane];
        for (int k = 0; k < Kk; ++k) {
            float best = -INFINITY; int bidx = 0;
#pragma unroll
            for (int i = 0; i < Nn / 64; ++i)
                if (v[i] > best) { best = v[i]; bidx = i * 64 + lane; }
#pragma unroll
            for (int m = 1; m < 64; m <<= 1) {
                float ov = __shfl_xor(best, m);
                int oi = __shfl_xor(bidx, m);
                if (ov > best || (ov == best && oi < bidx)) { best = ov; bidx = oi; }
            }
            if (lane == 0) { zsc[k] = best; zidx[k] = bidx; }
            if ((bidx & 63) == lane) {
                int slot = bidx >> 6;
#pragma unroll
                for (int i = 0; i < Nn / 64; ++i)
                    if (i == slot) v[i] = -INFINITY;
            }
        }
    }
    __syncthreads();
    for (int idx = tid; idx < Kk * Ee; idx += 256) {
        int k = idx >> 7, e = idx & 127;
        zsh[k][e] = ent[((size_t)b * Nn + zidx[k]) * Ee + e];
    }
    __syncthreads();
    if (tid < Kk) {
        float s = 0.f;
        for (int e = 0; e < Ee; ++e) { float v = zsh[tid][e]; s += v * v; }
        znorm[tid] = s;
    }
    __syncthreads();

    int f = fc * S2F + tid;
    const float* fp = factX + ((size_t)b * Ff + f) * Ee;
    float acc[Kk];
#pragma unroll
    for (int k = 0; k < Kk; ++k) acc[k] = 0.f;
    float nf = 0.f;
#pragma unroll 4
    for (int e0 = 0; e0 < Ee; e0 += 4) {
        float4 v = *(const float4*)(fp + e0);
        nf += v.x * v.x + v.y * v.y + v.z * v.z + v.w * v.w;
#pragma unroll
        for (int k = 0; k < Kk; ++k) {
            float4 z = *(const float4*)&zsh[k][e0];
            acc[k] += z.x * v.x + z.y * v.y + z.z * v.z + z.w * v.w;
        }
    }
    float base = s2b[f] - 0.5f * nf;   // -INF for invalid facts
    float sc[Kk];
#pragma unroll
    for (int k = 0; k < Kk; ++k) sc[k] = base + acc[k] - 0.5f * znorm[k];
    for (int o = 32; o; o >>= 1)
#pragma unroll
        for (int k = 0; k < Kk; ++k) sc[k] = fmaxf(sc[k], __shfl_down(sc[k], o));
    if ((tid & 63) == 0)
#pragma unroll
        for (int k = 0; k < Kk; ++k) red[wv][k] = sc[k];
    __syncthreads();
    if (tid < Kk) {
        float m = fmaxf(fmaxf(red[0][tid], red[1][tid]), fmaxf(red[2][tid], red[3][tid]));
        // max_f min(exp(s_f), z) == min(exp(max_f s_f), z)
        rules[tid] = fminf(expf(m), zsc[tid]);
    }
    __syncthreads();
    if (tid == 0) {
        float g = rules[0];
#pragma unroll
        for (int k = 1; k < Kk; ++k) g = fmaxf(g, rules[k]);
        atomic_fmax_pos(out + b, g);   // ONE atomic per block
    }
}

extern "C" void kernel_launch(void* const* d_in, const int* in_sizes, int n_in,
                              void* d_out, int out_size, void* d_ws, size_t ws_size,
                              hipStream_t stream) {
    const float* rel  = (const float*)d_in[0];
    const float* arg1 = (const float*)d_in[1];
    const float* arg2 = (const float*)d_in[2];
    const float* frel = (const float*)d_in[3];
    const float* fa1  = (const float*)d_in[4];
    const float* fa2  = (const float*)d_in[5];
    const float* ent  = (const float*)d_in[6];
    const float* hopW = (const float*)d_in[7];
    const float* hopb = (const float*)d_in[8];
    const int* nb_facts    = (const int*)d_in[9];
    const int* nb_entities = (const int*)d_in[10];
    float* out = (float*)d_out;

    float* ws = (float*)d_ws;
    size_t off = 0;
    float* c0       = ws + off; off += (size_t)Bb * Ff;
    float* c1       = ws + off; off += (size_t)Bb * Ff;
    float* s2b0     = ws + off; off += (size_t)Bb * Ff;
    float* s2b1     = ws + off; off += (size_t)Bb * Ff;
    float* sp0      = ws + off; off += (size_t)Bb * Nn;
    float* sp1      = ws + off; off += (size_t)Bb * Nn;
    float* ent_norm = ws + off; off += (size_t)Bb * Nn;
    off = (off + 7) & ~(size_t)7;   // 32B-align the split tensors
    unsigned short* B0 = (unsigned short*)(ws + off); off += (size_t)Bb * 16 * Ff * 8;
    unsigned short* B1 = (unsigned short*)(ws + off); off += (size_t)Bb * 16 * Ff * 8;

    hipMemsetAsync(d_out, 0, (size_t)out_size * sizeof(float), stream);
    k_pfe<<<dim3(128 + 4096 + Bb * Nn / 4), 256, 0, stream>>>(
        rel, arg1, arg2, frel, fa1, fa2, ent, hopW, hopb, nb_facts,
        B0, B1, ent_norm, c0, c1, s2b0, s2b1, sp0, sp1, out);
    k_spmax_mfma<<<dim3(32 * 8 * FS), 512, 0, stream>>>(ent, B0, B1, c0, c1, ent_norm,
                                                        nb_facts, nb_entities, sp0, sp1);
    k_s2t<<<dim3(S2FC, Bb, 2), 256, 0, stream>>>(ent, fa1, fa2, s2b0, s2b1,
                                                 sp0, sp1, nb_facts, out);
}

// Round 5
// 224.250 us; speedup vs baseline: 1.0731x; 1.0731x over previous
//
#include <hip/hip_runtime.h>
#include <math.h>

#define Bb 16
#define Nn 2048
#define Ff 2048
#define Ee 128
#define Kk 10
#define S2FC 8              // fact chunks in k_s2t
#define S2F (Ff / S2FC)     // 256 facts per block

typedef __attribute__((ext_vector_type(8))) short short8;
typedef __attribute__((ext_vector_type(4))) float f32x4;
typedef unsigned int u32;

// ---------------- helpers ----------------
__device__ inline float wave_sum(float x) {
    for (int o = 32; o; o >>= 1) x += __shfl_down(x, o);
    return x;  // valid in lane 0
}

// split fp32 -> bf16 hi (truncate) + bf16 lo (truncate of exact remainder)
__device__ inline void bsplit(float x, unsigned short& h, unsigned short& l) {
    unsigned int u = __float_as_uint(x);
    h = (unsigned short)(u >> 16);
    float hf = __uint_as_float(u & 0xFFFF0000u);
    l = (unsigned short)(__float_as_uint(x - hf) >> 16);
}

__device__ inline void atomic_fmax_pos(float* addr, float v) {
    // valid for non-negative floats: bit pattern order == float order
    atomicMax((unsigned int*)addr, __float_as_uint(v));
}

// async global->LDS, 16B per lane; LDS dest = wave-uniform base + lane*16
__device__ inline void gload_lds16(const void* g, void* l) {
    __builtin_amdgcn_global_load_lds(
        (const __attribute__((address_space(1))) u32*)g,
        (__attribute__((address_space(3))) u32*)l, 16, 0, 0);
}

// B layout: per b (1 MB): chunk c (32 KB, 64 facts) -> swizzled
//   off = oct*2048 + f*32 + p*16  (f = fact&63, p: 0=hi8,1=lo8)
//   phys = off ^ (((off>>7)&7)<<4)   // XOR f2,f3,f4 into (p,f0,f1): involution
// makes ds_read_b128 of a fragment column hit 2 lanes/16B-slot (= stride-1 baseline)

// ---------------- K1: pfe = facts(+inline hops) [0..127] + fact pre-split [128..4223]
//                       + entity norms / sp zero-init [4224..12415] ----------------
__global__ __launch_bounds__(256) void k_pfe(
    const float* __restrict__ rel, const float* __restrict__ arg1,
    const float* __restrict__ arg2, const float* __restrict__ frel,
    const float* __restrict__ fa1, const float* __restrict__ fa2,
    const float* __restrict__ ent, const float* __restrict__ hop_W,
    const float* __restrict__ hop_b, const int* __restrict__ nb_facts,
    unsigned short* __restrict__ B0, unsigned short* __restrict__ B1,
    float* __restrict__ ent_norm, float* __restrict__ c0, float* __restrict__ c1,
    float* __restrict__ s2b0, float* __restrict__ s2b1,
    float* __restrict__ sp0, float* __restrict__ sp1, float* __restrict__ out) {
    int bx = blockIdx.x;
    int tid = threadIdx.x;
    if (bx < 128) {
        // ---- facts: 256 facts/block, hops recomputed per block (identical fp order) ----
        int fcb = bx & 7, b = bx >> 3;
        int nbf = nb_facts[b];
        if (fcb * 256 >= nbf) {
            // whole block past valid facts: outputs are exactly -INF, skip all compute
            int f = fcb * 256 + tid;
            size_t o = (size_t)b * Ff + f;
            const float NI = -INFINITY;
            c0[o] = NI; c1[o] = NI; s2b0[o] = NI; s2b1[o] = NI;
            return;
        }
        __shared__ float q[7][Ee];     // rel, arg1, arg2, h10(rj0), h11(rj2), h20(rj1), h21(rj3)
        __shared__ float bred[4];
        if (tid < 128) {
            q[0][tid] = rel[b * Ee + tid];
            q[1][tid] = arg1[b * Ee + tid];
            q[2][tid] = arg2[b * Ee + tid];
        }
        __syncthreads();
        {   // hop projections: threads 0-127 do rj0,rj1; threads 128-255 do rj2,rj3
            int e = tid & 127, hf = tid >> 7;
            const float* W0 = hop_W + (size_t)(hf * 2) * Ee * Ee;
            const float* W1 = W0 + (size_t)Ee * Ee;
            float a0 = hop_b[(hf * 2) * Ee + e];
            float a1 = hop_b[(hf * 2 + 1) * Ee + e];
            for (int qq = 0; qq < Ee; ++qq) {
                float rq = q[0][qq];
                a0 += rq * W0[qq * Ee + e];
                a1 += rq * W1[qq * Ee + e];
            }
            q[3 + hf][e] = a0;   // hf0 -> q3 (h1 r0), hf1 -> q4 (h1 r1)
            q[5 + hf][e] = a1;   // hf0 -> q5 (h2 r0), hf1 -> q6 (h2 r1)
        }
        __syncthreads();

        int f = fcb * 256 + tid;
        const float* pr = frel + ((size_t)b * Ff + f) * Ee;
        const float* p1 = fa1 + ((size_t)b * Ff + f) * Ee;
        const float* p2 = fa2 + ((size_t)b * Ff + f) * Ee;
        float d_rr = 0, d_a11 = 0, d_a22 = 0, d_h10 = 0, d_h11 = 0, d_h20 = 0, d_h21 = 0;
        float d_a12 = 0, d_a21 = 0, n1 = 0, n2 = 0;
#pragma unroll 8
        for (int e0 = 0; e0 < Ee; e0 += 4) {
            float4 vr4 = *(const float4*)(pr + e0);
            float4 v14 = *(const float4*)(p1 + e0);
            float4 v24 = *(const float4*)(p2 + e0);
            const float* vrp = (const float*)&vr4;
            const float* v1p = (const float*)&v14;
            const float* v2p = (const float*)&v24;
#pragma unroll
            for (int j = 0; j < 4; ++j) {
                int e = e0 + j;
                float fr = vrp[j], f1 = v1p[j], f2 = v2p[j];
                float t;
                t = q[0][e] - fr; d_rr  += t * t;
                t = q[1][e] - f1; d_a11 += t * t;
                t = q[2][e] - f2; d_a22 += t * t;
                t = q[3][e] - fr; d_h10 += t * t;
                t = q[4][e] - fr; d_h11 += t * t;
                t = q[5][e] - fr; d_h20 += t * t;
                t = q[6][e] - fr; d_h21 += t * t;
                t = q[1][e] - f2; d_a12 += t * t;
                t = q[2][e] - f1; d_a21 += t * t;
                n1 += f1 * f1; n2 += f2 * f2;
            }
        }
        bool valid = f < nbf;
        const float NI = -INFINITY;
        size_t o = (size_t)b * Ff + f;
        c0[o]   = valid ? (-0.5f * (d_h10 + d_a11 + n2)) : NI;
        c1[o]   = valid ? (-0.5f * (d_h11 + d_a12 + n1)) : NI;
        s2b0[o] = valid ? (-0.5f * (d_h20 + d_a22)) : NI;
        s2b1[o] = valid ? (-0.5f * (d_h21 + d_a21)) : NI;
        // scores_0: block-level max of lsc, ONE atomic per block
        float lsc = valid ? (-0.5f * (d_rr + d_a11 + d_a22)) : NI;
        for (int m = 32; m; m >>= 1) lsc = fmaxf(lsc, __shfl_down(lsc, m));
        if ((tid & 63) == 0) bred[tid >> 6] = lsc;
        __syncthreads();
        if (tid == 0) {
            float m = fmaxf(fmaxf(bred[0], bred[1]), fmaxf(bred[2], bred[3]));
            atomic_fmax_pos(out + b, expf(m));
        }
    } else if (bx < 128 + 4096) {
        // ---- fact pre-split into chunk-blocked swizzled layout (LDS transpose) ----
        __shared__ uint4 tlds[16 * 33];   // [f(16)][stride 33: oct(16)*2 + pad]
        int bxx = bx - 128;
        int y = bxx >> 11, bxi = bxx & 2047;
        int oct = tid & 15, fl = tid >> 4;
        int b = bxi >> 7, fbase = (bxi & 127) * 16;
        const float* src = (y == 0) ? fa2 : fa1;    // r=0 scans fa2, r=1 scans fa1
        const float* s = src + ((size_t)b * Ff + fbase + fl) * Ee + oct * 8;
        float4 v0 = *(const float4*)s;
        float4 v1 = *(const float4*)(s + 4);
        float xs[8] = {v0.x, v0.y, v0.z, v0.w, v1.x, v1.y, v1.z, v1.w};
        unsigned short hi[8], lo[8];
#pragma unroll
        for (int j = 0; j < 8; ++j) bsplit(xs[j], hi[j], lo[j]);
        uint4 ph, pl;
        ph.x = (unsigned)hi[0] | ((unsigned)hi[1] << 16);
        ph.y = (unsigned)hi[2] | ((unsigned)hi[3] << 16);
        ph.z = (unsigned)hi[4] | ((unsigned)hi[5] << 16);
        ph.w = (unsigned)hi[6] | ((unsigned)hi[7] << 16);
        pl.x = (unsigned)lo[0] | ((unsigned)lo[1] << 16);
        pl.y = (unsigned)lo[2] | ((unsigned)lo[3] << 16);
        pl.z = (unsigned)lo[4] | ((unsigned)lo[5] << 16);
        pl.w = (unsigned)lo[6] | ((unsigned)lo[7] << 16);
        tlds[fl * 33 + oct * 2]     = ph;
        tlds[fl * 33 + oct * 2 + 1] = pl;
        __syncthreads();
        // write phase: physical slot s within 512B run; decode (fl,part) = unswizzle(s)
        int F4 = (fbase >> 4) & 1, F5 = (fbase >> 5) & 1;
        unsigned char* ob = (unsigned char*)((y == 0) ? B0 : B1) +
                            (((size_t)b << 20) + (size_t)(fbase >> 6) * 32768 +
                             F5 * 1024 + F4 * 512);
#pragma unroll
        for (int uu = 0; uu < 2; ++uu) {
            int u = tid + uu * 256;
            int o = u >> 5, sS = u & 31;
            int s0 = sS & 1, s1 = (sS >> 1) & 1, s2 = (sS >> 2) & 1;
            int s3 = (sS >> 3) & 1, s4 = (sS >> 4) & 1;
            int part = s0 ^ s3;
            int fll = (s1 ^ s4) | ((s2 ^ F4) << 1) | (s3 << 2) | (s4 << 3);
            *(uint4*)(ob + o * 2048 + sS * 16) = tlds[fll * 33 + o * 2 + part];
        }
    } else {
        // ---- entity self-norms + sp zero-init: 8192 blocks, 4 rows each ----
        int row  = (bx - (128 + 4096)) * 4 + (tid >> 6);
        int lane = tid & 63;
        const float* p = ent + (size_t)row * Ee;
        float a = p[lane], c = p[lane + 64];
        float s = wave_sum(a * a + c * c);
        if (lane == 0) {
            ent_norm[row] = s;
            sp0[row] = 0.0f;   // dead tiles never get stored by k_spmax
            sp1[row] = 0.0f;
        }
    }
}

// ---------------- K2: fused bias+max GEMM, B chunk staged via global_load_lds ----
#define BMs 256

__global__ __launch_bounds__(512, 2) void k_spmax_mfma(
    const float* __restrict__ ent, const unsigned short* __restrict__ B0,
    const unsigned short* __restrict__ B1, const float* __restrict__ c0,
    const float* __restrict__ c1, const float* __restrict__ ent_norm,
    const int* __restrict__ nb_facts, const int* __restrict__ nb_entities,
    float* __restrict__ sp0, float* __restrict__ sp1) {
    // same-slice blocks are 32 apart in bid -> same XCD (mod 8)
    int bid = blockIdx.x;
    int br = bid & 31, nblk = bid >> 5;
    int b = br >> 1, r = br & 1;
    const unsigned short* Bt = (r == 0) ? B0 : B1;
    const float* cb = ((r == 0) ? c0 : c1) + (size_t)b * Ff;
    float* sp = ((r == 0) ? sp0 : sp1) + (size_t)b * Nn;

    int tid = threadIdx.x;
    int ne = nb_entities[b];
    if (nblk * BMs >= ne) return;            // sp pre-zeroed; nothing to do
    int nch = (nb_facts[b] + 63) >> 6;       // live fact chunks (16..32)

    __shared__ uint4 ldsB4[2 * 2048];        // 64KB: double-buffered B chunk

    int wave = tid >> 6, lane = tid & 63;
    int wm = wave >> 1, wn = wave & 1;       // wm 0..3, wn 0..1
    int lane15 = lane & 15, quad = lane >> 4;

    // ---- A-hi and A-lo fragments, both in registers ----
    short8 ah[4][4], al[4][4];
    {
        const float* abase = ent + ((size_t)b * Nn + (size_t)nblk * BMs + wm * 64) * Ee;
#pragma unroll
        for (int i = 0; i < 4; ++i)
#pragma unroll
            for (int ks = 0; ks < 4; ++ks) {
                const float* p = abase + (size_t)(i * 16 + lane15) * Ee + ks * 32 + quad * 8;
                float4 v0 = *(const float4*)p;
                float4 v1 = *(const float4*)(p + 4);
                float xs[8] = {v0.x, v0.y, v0.z, v0.w, v1.x, v1.y, v1.z, v1.w};
                short8 hi8, lo8;
#pragma unroll
                for (int j = 0; j < 8; ++j) {
                    unsigned short hh, ll;
                    bsplit(xs[j], hh, ll);
                    hi8[j] = (short)hh;
                    lo8[j] = (short)ll;
                }
                ah[i][ks] = hi8;
                al[i][ks] = lo8;
            }
    }

    // lane-constant swizzled B offsets (bytes within chunk, minus oct term)
    int offA = (wn * 32 + lane15) * 32;
    int physA0 = offA ^ (((offA >> 7) & 7) << 4);
    int offB = offA + 512;
    int physB0 = offB ^ (((offB >> 7) & 7) << 4);
    int qoff = quad * 2048;

    unsigned char* ldsB = (unsigned char*)ldsB4;
    const unsigned char* gB = (const unsigned char*)Bt + ((size_t)b << 20);

    // prologue: stage chunk 0 into buf 0 (each wave: 4 x 1KB segments)
#pragma unroll
    for (int t = 0; t < 4; ++t) {
        int seg = t * 8 + wave;
        gload_lds16(gB + seg * 1024 + lane * 16, ldsB + seg * 1024);
    }
    __syncthreads();   // drains vmcnt -> chunk 0 resident

    float mmax[4][4];
#pragma unroll
    for (int i = 0; i < 4; ++i)
#pragma unroll
        for (int rr = 0; rr < 4; ++rr) mmax[i][rr] = -INFINITY;

    int cur = 0;
    for (int c = 0; c < nch; ++c) {
        if (c + 1 < nch) {    // stage next chunk into other buffer (in flight over MFMAs)
            const unsigned char* gc = gB + (size_t)(c + 1) * 32768;
            unsigned char* lb = ldsB + (cur ^ 1) * 32768;
#pragma unroll
            for (int t = 0; t < 4; ++t) {
                int seg = t * 8 + wave;
                gload_lds16(gc + seg * 1024 + lane * 16, lb + seg * 1024);
            }
        }
        float cj0 = cb[c * 64 + wn * 32 + lane15];
        float cj1 = cb[c * 64 + wn * 32 + 16 + lane15];
        f32x4 acc[4][2];
#pragma unroll
        for (int i = 0; i < 4; ++i) {
            acc[i][0] = (f32x4){cj0, cj0, cj0, cj0};   // bias pre-loaded into accumulator
            acc[i][1] = (f32x4){cj1, cj1, cj1, cj1};
        }
        const unsigned char* bb = ldsB + cur * 32768;
#pragma unroll
        for (int ks = 0; ks < 4; ++ks) {
            const unsigned char* bk = bb + ks * 8192 + qoff;
            short8 bh0 = *(const short8*)(bk + physA0);
            short8 bl0 = *(const short8*)(bk + (physA0 ^ 16));
            short8 bh1 = *(const short8*)(bk + physB0);
            short8 bl1 = *(const short8*)(bk + (physB0 ^ 16));
#pragma unroll
            for (int i = 0; i < 4; ++i) {
                acc[i][0] = __builtin_amdgcn_mfma_f32_16x16x32_bf16(ah[i][ks], bh0, acc[i][0], 0, 0, 0);
                acc[i][0] = __builtin_amdgcn_mfma_f32_16x16x32_bf16(al[i][ks], bh0, acc[i][0], 0, 0, 0);
                acc[i][0] = __builtin_amdgcn_mfma_f32_16x16x32_bf16(ah[i][ks], bl0, acc[i][0], 0, 0, 0);
                acc[i][1] = __builtin_amdgcn_mfma_f32_16x16x32_bf16(ah[i][ks], bh1, acc[i][1], 0, 0, 0);
                acc[i][1] = __builtin_amdgcn_mfma_f32_16x16x32_bf16(al[i][ks], bh1, acc[i][1], 0, 0, 0);
                acc[i][1] = __builtin_amdgcn_mfma_f32_16x16x32_bf16(ah[i][ks], bl1, acc[i][1], 0, 0, 0);
            }
        }

#pragma unroll
        for (int j = 0; j < 2; ++j)
#pragma unroll
            for (int i = 0; i < 4; ++i)
#pragma unroll
                for (int rr = 0; rr < 4; ++rr)
                    mmax[i][rr] = fmaxf(mmax[i][rr], acc[i][j][rr]);

        __syncthreads();   // next-chunk stage complete + all reads of cur done
        cur ^= 1;
    }

    // ---- reduce across 16 lane15 columns in-wave, then across wn via LDS (reuse ldsB) ----
    float* red = (float*)ldsB;   // [256][2]
#pragma unroll
    for (int i = 0; i < 4; ++i)
#pragma unroll
        for (int rr = 0; rr < 4; ++rr) {
            float v = mmax[i][rr];
#pragma unroll
            for (int m = 1; m < 16; m <<= 1) v = fmaxf(v, __shfl_xor(v, m));
            if (lane15 == 0) red[(wm * 64 + i * 16 + quad * 4 + rr) * 2 + wn] = v;
        }
    __syncthreads();
    if (tid < BMs) {
        float m = fmaxf(red[tid * 2], red[tid * 2 + 1]);
        int n = nblk * BMs + tid;
        if (n < ne)
            sp[n] = expf(m - 0.5f * ent_norm[(size_t)b * Nn + n]);
    }
}

// ---------------- K3: tail = in-block topk (wave 0) + second-hop rescore + ONE atomic/block ----
__global__ __launch_bounds__(256) void k_s2t(
    const float* __restrict__ ent, const float* __restrict__ fa1,
    const float* __restrict__ fa2, const float* __restrict__ s2b0,
    const float* __restrict__ s2b1, const float* __restrict__ sp0,
    const float* __restrict__ sp1, const int* __restrict__ nb_facts,
    float* __restrict__ out) {
    int fc = blockIdx.x, b = blockIdx.y, r = blockIdx.z;
    if (fc * S2F >= nb_facts[b]) return;   // all facts -INF: atomic would be max(out, 0) = no-op
    const float* factX = (r == 0) ? fa1 : fa2;   // z compares vs fa1 (r=0) / fa2 (r=1)
    const float* s2b   = ((r == 0) ? s2b0 : s2b1) + (size_t)b * Ff;
    const float* sp    = ((r == 0) ? sp0 : sp1) + (size_t)b * Nn;

    __shared__ float zsc[Kk];
    __shared__ int   zidx[Kk];
    __shared__ float zsh[Kk][Ee];
    __shared__ float znorm[Kk];
    __shared__ float red[4][Kk];
    __shared__ float rules[Kk];

    int tid = threadIdx.x;
    int wv = tid >> 6, lane = tid & 63;

    if (wv == 0) {   // single-wave top-K, jax-stable ties (lowest index wins)
        float v[Nn / 64];
#pragma unroll
        for (int i = 0; i < Nn / 64; ++i) v[i] = sp[i * 64 + lane];
        for (int k = 0; k < Kk; ++k) {
            float best = -INFINITY; int bidx = 0;
#pragma unroll
            for (int i = 0; i < Nn / 64; ++i)
                if (v[i] > best) { best = v[i]; bidx = i * 64 + lane; }
#pragma unroll
            for (int m = 1; m < 64; m <<= 1) {
                float ov = __shfl_xor(best, m);
                int oi = __shfl_xor(bidx, m);
                if (ov > best || (ov == best && oi < bidx)) { best = ov; bidx = oi; }
            }
            if (lane == 0) { zsc[k] = best; zidx[k] = bidx; }
            if ((bidx & 63) == lane) {
                int slot = bidx >> 6;
#pragma unroll
                for (int i = 0; i < Nn / 64; ++i)
                    if (i == slot) v[i] = -INFINITY;
            }
        }
    }
    __syncthreads();
    for (int idx = tid; idx < Kk * Ee; idx += 256) {
        int k = idx >> 7, e = idx & 127;
        zsh[k][e] = ent[((size_t)b * Nn + zidx[k]) * Ee + e];
    }
    __syncthreads();
    if (tid < Kk) {
        float s = 0.f;
        for (int e = 0; e < Ee; ++e) { float v = zsh[tid][e]; s += v * v; }
        znorm[tid] = s;
    }
    __syncthreads();

    int f = fc * S2F + tid;
    const float* fp = factX + ((size_t)b * Ff + f) * Ee;
    float acc[Kk];
#pragma unroll
    for (int k = 0; k < Kk; ++k) acc[k] = 0.f;
    float nf = 0.f;
#pragma unroll 4
    for (int e0 = 0; e0 < Ee; e0 += 4) {
        float4 v = *(const float4*)(fp + e0);
        nf += v.x * v.x + v.y * v.y + v.z * v.z + v.w * v.w;
#pragma unroll
        for (int k = 0; k < Kk; ++k) {
            float4 z = *(const float4*)&zsh[k][e0];
            acc[k] += z.x * v.x + z.y * v.y + z.z * v.z + z.w * v.w;
        }
    }
    float base = s2b[f] - 0.5f * nf;   // -INF for invalid facts
    float sc[Kk];
#pragma unroll
    for (int k = 0; k < Kk; ++k) sc[k] = base + acc[k] - 0.5f * znorm[k];
    for (int o = 32; o; o >>= 1)
#pragma unroll
        for (int k = 0; k < Kk; ++k) sc[k] = fmaxf(sc[k], __shfl_down(sc[k], o));
    if ((tid & 63) == 0)
#pragma unroll
        for (int k = 0; k < Kk; ++k) red[wv][k] = sc[k];
    __syncthreads();
    if (tid < Kk) {
        float m = fmaxf(fmaxf(red[0][tid], red[1][tid]), fmaxf(red[2][tid], red[3][tid]));
        // max_f min(exp(s_f), z) == min(exp(max_f s_f), z)
        rules[tid] = fminf(expf(m), zsc[tid]);
    }
    __syncthreads();
    if (tid == 0) {
        float g = rules[0];
#pragma unroll
        for (int k = 1; k < Kk; ++k) g = fmaxf(g, rules[k]);
        atomic_fmax_pos(out + b, g);   // ONE atomic per block
    }
}

extern "C" void kernel_launch(void* const* d_in, const int* in_sizes, int n_in,
                              void* d_out, int out_size, void* d_ws, size_t ws_size,
                              hipStream_t stream) {
    const float* rel  = (const float*)d_in[0];
    const float* arg1 = (const float*)d_in[1];
    const float* arg2 = (const float*)d_in[2];
    const float* frel = (const float*)d_in[3];
    const float* fa1  = (const float*)d_in[4];
    const float* fa2  = (const float*)d_in[5];
    const float* ent  = (const float*)d_in[6];
    const float* hopW = (const float*)d_in[7];
    const float* hopb = (const float*)d_in[8];
    const int* nb_facts    = (const int*)d_in[9];
    const int* nb_entities = (const int*)d_in[10];
    float* out = (float*)d_out;

    float* ws = (float*)d_ws;
    size_t off = 0;
    float* c0       = ws + off; off += (size_t)Bb * Ff;
    float* c1       = ws + off; off += (size_t)Bb * Ff;
    float* s2b0     = ws + off; off += (size_t)Bb * Ff;
    float* s2b1     = ws + off; off += (size_t)Bb * Ff;
    float* sp0      = ws + off; off += (size_t)Bb * Nn;
    float* sp1      = ws + off; off += (size_t)Bb * Nn;
    float* ent_norm = ws + off; off += (size_t)Bb * Nn;
    off = (off + 7) & ~(size_t)7;   // 32B-align the split tensors
    unsigned short* B0 = (unsigned short*)(ws + off); off += (size_t)Bb * 16 * Ff * 8;
    unsigned short* B1 = (unsigned short*)(ws + off); off += (size_t)Bb * 16 * Ff * 8;

    hipMemsetAsync(d_out, 0, (size_t)out_size * sizeof(float), stream);
    k_pfe<<<dim3(128 + 4096 + Bb * Nn / 4), 256, 0, stream>>>(
        rel, arg1, arg2, frel, fa1, fa2, ent, hopW, hopb, nb_facts,
        B0, B1, ent_norm, c0, c1, s2b0, s2b1, sp0, sp1, out);
    k_spmax_mfma<<<dim3(32 * 8), 512, 0, stream>>>(ent, B0, B1, c0, c1, ent_norm,
                                                   nb_facts, nb_entities, sp0, sp1);
    k_s2t<<<dim3(S2FC, Bb, 2), 256, 0, stream>>>(ent, fa1, fa2, s2b0, s2b1,
                                                 sp0, sp1, nb_facts, out);
}